// Round 3
// baseline (424.711 us; speedup 1.0000x reference)
//
#include <hip/hip_runtime.h>

#define N_NODES 50000
#define N_EDGES 800000
#define F_IN    128
#define HID     128
#define F_OUT   64
#define BN_EPS  1e-5f
#define NBUCKET ((N_NODES + 31) / 32)   // 1563

typedef __bf16 bf16x8 __attribute__((ext_vector_type(8)));
typedef float  f32x4  __attribute__((ext_vector_type(4)));

static inline size_t align_up(size_t x, size_t a){ return (x + a - 1) / a * a; }

__device__ __forceinline__ float bflo(unsigned u){ return __uint_as_float(u << 16); }
__device__ __forceinline__ float bfhi(unsigned u){ return __uint_as_float(u & 0xffff0000u); }
__device__ __forceinline__ unsigned packbf(float a, float b){
  __bf16 ha = (__bf16)a, hb = (__bf16)b;
  unsigned short ua = __builtin_bit_cast(unsigned short, ha);
  unsigned short ub = __builtin_bit_cast(unsigned short, hb);
  return (unsigned)ua | ((unsigned)ub << 16);
}

// ---------------- CSR build: hist -> scan -> bucket-scatter -> bucket-sort ----------------

__global__ void k_hist(const int* __restrict__ dst, int* __restrict__ cnt){
  int e = blockIdx.x * blockDim.x + threadIdx.x;
  if(e < N_EDGES) atomicAdd(&cnt[dst[e]], 1);
}

__global__ void k_scanA(const int* __restrict__ cnt, int* __restrict__ rp, int* __restrict__ part){
  __shared__ int s[256];
  int i = blockIdx.x * 256 + threadIdx.x;
  int v = (i < N_NODES) ? cnt[i] : 0;
  s[threadIdx.x] = v;
  __syncthreads();
  for(int off = 1; off < 256; off <<= 1){
    int t = (threadIdx.x >= off) ? s[threadIdx.x - off] : 0;
    __syncthreads();
    s[threadIdx.x] += t;
    __syncthreads();
  }
  if(i < N_NODES) rp[i] = s[threadIdx.x] - v;
  if(threadIdx.x == 255) part[blockIdx.x] = s[255];
}

__global__ void k_scanB(int* __restrict__ part, int nb){
  __shared__ int s[256];
  int v = (threadIdx.x < nb) ? part[threadIdx.x] : 0;
  s[threadIdx.x] = v;
  __syncthreads();
  for(int off = 1; off < 256; off <<= 1){
    int t = (threadIdx.x >= off) ? s[threadIdx.x - off] : 0;
    __syncthreads();
    s[threadIdx.x] += t;
    __syncthreads();
  }
  part[threadIdx.x] = s[threadIdx.x] - v;
}

__global__ void k_scanC(int* __restrict__ rp, const int* __restrict__ part){
  int i = blockIdx.x * 256 + threadIdx.x;
  if(i < N_NODES) rp[i] += part[blockIdx.x];
  if(i == 0) rp[N_NODES] = N_EDGES;
}

// Phase C: scatter edge to its 32-dst bucket region (cursor order within bucket).
// staged.y = src | (d_local << 20)
__global__ void k_bucket(const int* __restrict__ dst, const int* __restrict__ src,
                         const float* __restrict__ vals, const int* __restrict__ rp,
                         int* __restrict__ bcur, int2* __restrict__ staged){
  int e = blockIdx.x * blockDim.x + threadIdx.x;
  if(e >= N_EDGES) return;
  int d = dst[e];
  int b = d >> 5;
  int pos = rp[d & ~31] + atomicAdd(&bcur[b], 1);
  staged[pos] = make_int2(__float_as_int(vals[e]), src[e] | ((d & 31) << 20));
}

// Phase D: per-bucket exact placement via LDS cursors. Writes stay in ~4KB window.
__global__ __launch_bounds__(256) void k_sortB(const int2* __restrict__ staged,
    const int* __restrict__ rp, int2* __restrict__ epack){
  __shared__ int off[33];
  __shared__ int cur[32];
  int b = blockIdx.x;
  int d0 = b * 32;
  int nd = N_NODES - d0; if(nd > 32) nd = 32;
  int tid = threadIdx.x;
  if(tid <= nd) off[tid] = rp[d0 + tid];
  if(tid < 32) cur[tid] = 0;
  __syncthreads();
  int base = off[0];
  int cnt_b = off[nd] - base;
  for(int i = tid; i < cnt_b; i += 256){
    int2 e = staged[base + i];
    int dl = (e.y >> 20) & 31;
    int p = atomicAdd(&cur[dl], 1);
    epack[off[dl] + p] = make_int2(e.x, e.y & 0xffff);
  }
}

// ---------------- weight prep: frag-ordered bf16 tables ----------------
// b_frag convention: lane l holds B[k = ks*32 + (l>>4)*8 + i][c = nf*16 + (l&15)]

__global__ void k_prepW(const float* __restrict__ W1, const float* __restrict__ W2,
                        __bf16* __restrict__ W1f, __bf16* __restrict__ W2f){
  int t = blockIdx.x * 256 + threadIdx.x;
  if(t < 4096){
    int ks = t >> 9, rem = t & 511, nf = rem >> 6, l = rem & 63;
    int k = ks * 32 + (l >> 4) * 8, c = nf * 16 + (l & 15);
    bf16x8 v;
    #pragma unroll
    for(int i = 0; i < 8; i++) v[i] = (__bf16)W1[(size_t)(k + i) * HID + c];
    *(bf16x8*)(W1f + ((size_t)t << 3)) = v;
  } else if(t < 6144){
    int s = t - 4096;
    int ks = s >> 9, rem = s & 511, nf = rem >> 6, l = rem & 63;
    int k = ks * 32 + (l >> 4) * 8, c = nf * 16 + (l & 15);
    bf16x8 v;
    #pragma unroll
    for(int i = 0; i < 8; i++){
      int kk = k + i;
      float val = (c < 64) ? W2[(size_t)kk * F_OUT + c]
                           : W2[(size_t)(HID + kk) * F_OUT + (c - 64)];
      v[i] = (__bf16)val;
    }
    *(bf16x8*)(W2f + ((size_t)s << 3)) = v;
  }
}

// ---------------- X -> bf16 plane Sx [N][128] ----------------

__global__ __launch_bounds__(256) void k_cvtX(const float* __restrict__ X, __bf16* __restrict__ Sx){
  int t = blockIdx.x * 256 + threadIdx.x;
  if(t >= N_NODES * 16) return;
  int n = t >> 4;
  int c = (t & 15) * 8;
  const float* xp = X + (size_t)n * F_IN + c;
  f32x4 x0 = *(const f32x4*)xp;
  f32x4 x1 = *(const f32x4*)(xp + 4);
  bf16x8 v;
  #pragma unroll
  for(int i = 0; i < 4; i++){ v[i] = (__bf16)x0[i]; v[4 + i] = (__bf16)x1[i]; }
  *(bf16x8*)(Sx + (size_t)n * 128 + c) = v;
}

// ---------------- SpMM 1: Sa[w] = sum_e w_e * Sx[src_e]  (bf16, 128-wide) ----------------

__global__ __launch_bounds__(256) void k_spmm1(const __bf16* __restrict__ Sx,
    __bf16* __restrict__ Sa, const int2* __restrict__ epack, const int* __restrict__ rp){
  int w    = (int)((blockIdx.x * blockDim.x + threadIdx.x) >> 6);
  int lane = threadIdx.x & 63;
  if(w >= N_NODES) return;
  int beg = rp[w], end = rp[w + 1];
  float a0 = 0.f, a1 = 0.f;
  int e = beg;
  for(; e + 1 < end; e += 2){
    int2 p0 = epack[e], p1 = epack[e + 1];
    float w0 = __int_as_float(p0.x);
    float w1 = __int_as_float(p1.x);
    unsigned u0 = *(const unsigned*)(Sx + (size_t)p0.y * 128 + lane * 2);
    unsigned u1 = *(const unsigned*)(Sx + (size_t)p1.y * 128 + lane * 2);
    a0 = fmaf(w0, bflo(u0), a0); a1 = fmaf(w0, bfhi(u0), a1);
    a0 = fmaf(w1, bflo(u1), a0); a1 = fmaf(w1, bfhi(u1), a1);
  }
  if(e < end){
    int2 p = epack[e];
    float wt = __int_as_float(p.x);
    unsigned u = *(const unsigned*)(Sx + (size_t)p.y * 128 + lane * 2);
    a0 = fmaf(wt, bflo(u), a0); a1 = fmaf(wt, bfhi(u), a1);
  }
  *(unsigned*)(Sa + (size_t)w * 128 + lane * 2) = packbf(a0, a1);
}

// ---------------- GEMM 1 (MFMA): h_pre = [Sa|Sx] @ W1 + b1, + BN partials ----------------

__global__ __launch_bounds__(256) void k_gemm1(
    const __bf16* __restrict__ Sa, const __bf16* __restrict__ Sx,
    const __bf16* __restrict__ W1f, const float* __restrict__ b1,
    float* __restrict__ hpre, float* __restrict__ bn_acc){
  __shared__ float bnred[2][256];
  const int tid = threadIdx.x;
  const int lane = tid & 63, wid = tid >> 6;
  const int wm = wid >> 1, wn = wid & 1;
  const int lr = lane & 15, lk = (lane >> 4) * 8;
  const int rbase = blockIdx.x * 64 + wm * 32 + lr;

  f32x4 acc[2][4];
  #pragma unroll
  for(int m = 0; m < 2; m++)
    #pragma unroll
    for(int n = 0; n < 4; n++) acc[m][n] = (f32x4){0.f, 0.f, 0.f, 0.f};

  for(int ks = 0; ks < 8; ks++){
    const __bf16* src = (ks < 4) ? Sa : Sx;
    const int kb = (ks & 3) * 32 + lk;
    bf16x8 a[2], b[4];
    #pragma unroll
    for(int m = 0; m < 2; m++){
      int r = rbase + m * 16; if(r > N_NODES - 1) r = N_NODES - 1;
      a[m] = *(const bf16x8*)(src + (size_t)r * 128 + kb);
    }
    #pragma unroll
    for(int n = 0; n < 4; n++)
      b[n] = *(const bf16x8*)(W1f + (((ks * 8 + wn * 4 + n) * 64 + lane) << 3));
    #pragma unroll
    for(int m = 0; m < 2; m++)
      #pragma unroll
      for(int n = 0; n < 4; n++)
        acc[m][n] = __builtin_amdgcn_mfma_f32_16x16x32_bf16(a[m], b[n], acc[m][n], 0, 0, 0);
  }

  #pragma unroll
  for(int n = 0; n < 4; n++){
    int gc = wn * 64 + n * 16 + lr;
    float bias = b1[gc];
    float ps = 0.f, pq = 0.f;
    #pragma unroll
    for(int m = 0; m < 2; m++){
      int gr0 = blockIdx.x * 64 + wm * 32 + m * 16 + (lane >> 4) * 4;
      #pragma unroll
      for(int i = 0; i < 4; i++){
        int r = gr0 + i;
        if(r < N_NODES){
          float h = acc[m][n][i] + bias;
          hpre[(size_t)r * HID + gc] = h;
          ps += h; pq += h * h;
        }
      }
    }
    ps += __shfl_xor(ps, 16); ps += __shfl_xor(ps, 32);
    pq += __shfl_xor(pq, 16); pq += __shfl_xor(pq, 32);
    if(lane < 16){
      bnred[wm][gc] = ps;
      bnred[wm][128 + gc] = pq;
    }
  }
  __syncthreads();
  atomicAdd(&bn_acc[tid], bnred[0][tid] + bnred[1][tid]);
}

// ---------------- BN stats ----------------

__global__ void k_bnstats(const float* __restrict__ bn_acc, const float* __restrict__ gamma,
                          const float* __restrict__ beta, float* __restrict__ bn_sc){
  int c = threadIdx.x;
  if(c < HID){
    float mean = bn_acc[c] / (float)N_NODES;
    float var  = bn_acc[HID + c] / (float)N_NODES - mean * mean;
    float rs   = rsqrtf(var + BN_EPS);
    float sc   = gamma[c] * rs;
    bn_sc[c]       = sc;
    bn_sc[HID + c] = beta[c] - mean * sc;
  }
}

// ---------------- GEMM 2 (MFMA): BN+ReLU fused into A-frags ----------------

__global__ __launch_bounds__(256) void k_gemm2(
    const float* __restrict__ hpre, const __bf16* __restrict__ W2f,
    const float* __restrict__ b2, const float* __restrict__ bn_sc,
    __bf16* __restrict__ y2b, float* __restrict__ out){
  const int tid = threadIdx.x;
  const int lane = tid & 63, wid = tid >> 6;
  const int wm = wid >> 1, wn = wid & 1;
  const int lr = lane & 15, lk = (lane >> 4) * 8;
  const int rbase = blockIdx.x * 64 + wm * 32 + lr;

  f32x4 acc[2][4];
  #pragma unroll
  for(int m = 0; m < 2; m++)
    #pragma unroll
    for(int n = 0; n < 4; n++) acc[m][n] = (f32x4){0.f, 0.f, 0.f, 0.f};

  for(int ks = 0; ks < 4; ks++){
    int k0 = ks * 32 + lk;
    f32x4 sc0 = *(const f32x4*)(bn_sc + k0);
    f32x4 sc1 = *(const f32x4*)(bn_sc + k0 + 4);
    f32x4 sh0 = *(const f32x4*)(bn_sc + 128 + k0);
    f32x4 sh1 = *(const f32x4*)(bn_sc + 128 + k0 + 4);
    bf16x8 a[2], b[4];
    #pragma unroll
    for(int m = 0; m < 2; m++){
      int r = rbase + m * 16; if(r > N_NODES - 1) r = N_NODES - 1;
      const float* hp = hpre + (size_t)r * HID + k0;
      f32x4 h0 = *(const f32x4*)hp;
      f32x4 h1 = *(const f32x4*)(hp + 4);
      bf16x8 af;
      #pragma unroll
      for(int i = 0; i < 4; i++){
        af[i]     = (__bf16)fmaxf(0.f, fmaf(h0[i], sc0[i], sh0[i]));
        af[4 + i] = (__bf16)fmaxf(0.f, fmaf(h1[i], sc1[i], sh1[i]));
      }
      a[m] = af;
    }
    #pragma unroll
    for(int n = 0; n < 4; n++)
      b[n] = *(const bf16x8*)(W2f + (((ks * 8 + wn * 4 + n) * 64 + lane) << 3));
    #pragma unroll
    for(int m = 0; m < 2; m++)
      #pragma unroll
      for(int n = 0; n < 4; n++)
        acc[m][n] = __builtin_amdgcn_mfma_f32_16x16x32_bf16(a[m], b[n], acc[m][n], 0, 0, 0);
  }

  #pragma unroll
  for(int n = 0; n < 4; n++){
    int c = n * 16 + lr;
    float bias = (wn == 1) ? b2[c] : 0.f;
    #pragma unroll
    for(int m = 0; m < 2; m++){
      int gr0 = blockIdx.x * 64 + wm * 32 + m * 16 + (lane >> 4) * 4;
      #pragma unroll
      for(int i = 0; i < 4; i++){
        int r = gr0 + i;
        if(r < N_NODES){
          if(wn == 0) y2b[(size_t)r * F_OUT + c] = (__bf16)acc[m][n][i];
          else        out[(size_t)r * F_OUT + c] = acc[m][n][i] + bias;
        }
      }
    }
  }
}

// ---------------- SpMM 2: out += A @ y2 (bf16 gather, 2 edges per wave-iter) ----------------

__global__ __launch_bounds__(256) void k_spmm2(const __bf16* __restrict__ y2b,
    const int2* __restrict__ epack, const int* __restrict__ rp, float* __restrict__ out){
  int w    = (int)((blockIdx.x * blockDim.x + threadIdx.x) >> 6);
  int lane = threadIdx.x & 63;
  if(w >= N_NODES) return;
  int beg = rp[w], end = rp[w + 1];
  int half = lane >> 5, li = lane & 31;
  float a0 = 0.f, a1 = 0.f;
  for(int e = beg + half; e < end; e += 2){
    int2 p = epack[e];
    float wt = __int_as_float(p.x);
    unsigned u = *(const unsigned*)(y2b + (size_t)p.y * F_OUT + li * 2);
    a0 = fmaf(wt, bflo(u), a0);
    a1 = fmaf(wt, bfhi(u), a1);
  }
  a0 += __shfl_xor(a0, 32);
  a1 += __shfl_xor(a1, 32);
  if(lane < 32){
    float2 o = *(float2*)(out + (size_t)w * F_OUT + li * 2);
    o.x += a0; o.y += a1;
    *(float2*)(out + (size_t)w * F_OUT + li * 2) = o;
  }
}

// ---------------- launch ----------------

extern "C" void kernel_launch(void* const* d_in, const int* in_sizes, int n_in,
                              void* d_out, int out_size, void* d_ws, size_t ws_size,
                              hipStream_t stream){
  const float* X     = (const float*)d_in[0];
  const float* W1    = (const float*)d_in[1];
  const float* b1    = (const float*)d_in[2];
  const float* gamma = (const float*)d_in[3];
  const float* beta  = (const float*)d_in[4];
  const float* W2    = (const float*)d_in[5];
  const float* b2    = (const float*)d_in[6];
  const float* evals = (const float*)d_in[7];
  const int*   esrc  = (const int*)d_in[8];
  const int*   edst  = (const int*)d_in[9];
  float* out = (float*)d_out;

  char* ws = (char*)d_ws;
  size_t off = 0;
  auto carve = [&](size_t bytes) -> char* {
    off = align_up(off, 256);
    char* p = ws + off;
    off += bytes;
    return p;
  };
  int*     cnt    = (int*)    carve((size_t)N_NODES * 4);
  int*     rp     = (int*)    carve(((size_t)N_NODES + 1) * 4);
  int*     part   = (int*)    carve(256 * 4);
  float*   bn_acc = (float*)  carve(256 * 4);
  float*   bn_sc  = (float*)  carve(256 * 4);
  int*     bcur   = (int*)    carve((size_t)NBUCKET * 4);
  int2*    staged = (int2*)   carve((size_t)N_EDGES * 8);
  int2*    epack  = (int2*)   carve((size_t)N_EDGES * 8);
  __bf16*  W1f    = (__bf16*) carve((size_t)4096 * 8 * 2);
  __bf16*  W2f    = (__bf16*) carve((size_t)2048 * 8 * 2);
  __bf16*  Sa     = (__bf16*) carve((size_t)N_NODES * 128 * 2);
  __bf16*  Sx     = (__bf16*) carve((size_t)N_NODES * 128 * 2);
  float*   hpre   = (float*)  carve((size_t)N_NODES * HID * 4);
  __bf16*  y2b    = (__bf16*) carve((size_t)N_NODES * F_OUT * 2);

  hipMemsetAsync(cnt, 0, (size_t)N_NODES * 4, stream);
  hipMemsetAsync(bn_acc, 0, 256 * 4, stream);
  hipMemsetAsync(bcur, 0, (size_t)NBUCKET * 4, stream);

  const int SCAN_BLOCKS = (N_NODES + 255) / 256;  // 196

  k_hist<<<(N_EDGES + 255) / 256, 256, 0, stream>>>(edst, cnt);
  k_scanA<<<SCAN_BLOCKS, 256, 0, stream>>>(cnt, rp, part);
  k_scanB<<<1, 256, 0, stream>>>(part, SCAN_BLOCKS);
  k_scanC<<<SCAN_BLOCKS, 256, 0, stream>>>(rp, part);
  k_bucket<<<(N_EDGES + 255) / 256, 256, 0, stream>>>(edst, esrc, evals, rp, bcur, staged);
  k_sortB<<<NBUCKET, 256, 0, stream>>>(staged, rp, epack);

  k_prepW<<<24, 256, 0, stream>>>(W1, W2, W1f, W2f);
  k_cvtX<<<(N_NODES * 16 + 255) / 256, 256, 0, stream>>>(X, Sx);

  k_spmm1<<<N_NODES / 4, 256, 0, stream>>>(Sx, Sa, epack, rp);
  k_gemm1<<<(N_NODES + 63) / 64, 256, 0, stream>>>(Sa, Sx, W1f, b1, hpre, bn_acc);
  k_bnstats<<<1, 128, 0, stream>>>(bn_acc, gamma, beta, bn_sc);
  k_gemm2<<<(N_NODES + 63) / 64, 256, 0, stream>>>(hpre, W2f, b2, bn_sc, y2b, out);
  k_spmm2<<<N_NODES / 4, 256, 0, stream>>>(y2b, epack, rp, out);
}

// Round 4
// 255.670 us; speedup vs baseline: 1.6612x; 1.6612x over previous
//
#include <hip/hip_runtime.h>

#define N_NODES 50000
#define N_EDGES 800000
#define F_IN    128
#define HID     128
#define F_OUT   64
#define BN_EPS  1e-5f

#define NRANGES 196          // dst ranges of 256 nodes: ceil(50000/256)
#define NCHUNKS 196          // edge chunks of 4096: ceil(800000/4096)
#define CHUNK   4096

typedef __bf16 bf16x8 __attribute__((ext_vector_type(8)));
typedef float  f32x4  __attribute__((ext_vector_type(4)));

static inline size_t align_up(size_t x, size_t a){ return (x + a - 1) / a * a; }

__device__ __forceinline__ float bflo(unsigned u){ return __uint_as_float(u << 16); }
__device__ __forceinline__ float bfhi(unsigned u){ return __uint_as_float(u & 0xffff0000u); }
__device__ __forceinline__ unsigned packbf(float a, float b){
  __bf16 ha = (__bf16)a, hb = (__bf16)b;
  unsigned short ua = __builtin_bit_cast(unsigned short, ha);
  unsigned short ub = __builtin_bit_cast(unsigned short, hb);
  return (unsigned)ua | ((unsigned)ub << 16);
}

// ---------------- CSR build: 3-pass atomic-free partition ----------------

// Pass 1: per-chunk histogram over dst ranges (LDS atomics only).
__global__ __launch_bounds__(256) void k_pass1(const int* __restrict__ dst, int* __restrict__ Hcr){
  __shared__ int hist[NRANGES];
  int c = blockIdx.x, t = threadIdx.x;
  if(t < NRANGES) hist[t] = 0;
  __syncthreads();
  int e0 = c * CHUNK;
  #pragma unroll
  for(int k = 0; k < CHUNK / 256; k++){
    int e = e0 + k * 256 + t;
    if(e < N_EDGES) atomicAdd(&hist[dst[e] >> 8], 1);
  }
  __syncthreads();
  if(t < NRANGES) Hcr[c * NRANGES + t] = hist[t];
}

// Scan: Hcr[c][r] -> exclusive prefix over chunks (in place); rangeScan = scan of range totals.
// Also zeroes bn_acc.
__global__ __launch_bounds__(256) void k_scanH(int* __restrict__ Hcr, int* __restrict__ rangeScan,
                                               float* __restrict__ bn_acc){
  __shared__ int s[256];
  int t = threadIdx.x;
  int run = 0;
  if(t < NRANGES){
    for(int c = 0; c < NCHUNKS; c++){
      int v = Hcr[c * NRANGES + t];
      Hcr[c * NRANGES + t] = run;
      run += v;
    }
  }
  s[t] = (t < NRANGES) ? run : 0;
  __syncthreads();
  for(int off = 1; off < 256; off <<= 1){
    int v = (t >= off) ? s[t - off] : 0;
    __syncthreads();
    s[t] += v;
    __syncthreads();
  }
  if(t < NRANGES) rangeScan[t + 1] = s[t];
  if(t == 0) rangeScan[0] = 0;
  bn_acc[t] = 0.f;
}

// Pass 2: place edges into range-grouped staging at exact disjoint slots (no global atomics).
// staged.y = src | (d&255) << 16
__global__ __launch_bounds__(256) void k_pass2(const int* __restrict__ dst, const int* __restrict__ src,
    const float* __restrict__ vals, const int* __restrict__ Hcr,
    const int* __restrict__ rangeScan, int2* __restrict__ staged){
  __shared__ int cur[NRANGES];
  int c = blockIdx.x, t = threadIdx.x;
  if(t < NRANGES) cur[t] = rangeScan[t] + Hcr[c * NRANGES + t];
  __syncthreads();
  int e0 = c * CHUNK;
  #pragma unroll
  for(int k = 0; k < CHUNK / 256; k++){
    int e = e0 + k * 256 + t;
    if(e < N_EDGES){
      int d = dst[e];
      int pos = atomicAdd(&cur[d >> 8], 1);      // LDS atomic
      staged[pos] = make_int2(__float_as_int(vals[e]), src[e] | ((d & 255) << 16));
    }
  }
}

// Pass 3: one wg owns range r (256 dst, ~4K edges): write rp[] + final dst-sorted epack.
__global__ __launch_bounds__(256) void k_pass3(const int2* __restrict__ staged,
    const int* __restrict__ rangeScan, int2* __restrict__ epack, int* __restrict__ rp){
  __shared__ int cnt[256];
  __shared__ int pre[256];
  int r = blockIdx.x, t = threadIdx.x;
  int beg = rangeScan[r], end = rangeScan[r + 1];
  cnt[t] = 0;
  __syncthreads();
  for(int i = beg + t; i < end; i += 256)
    atomicAdd(&cnt[(staged[i].y >> 16) & 255], 1);
  __syncthreads();
  int v = cnt[t];
  pre[t] = v;
  __syncthreads();
  for(int off = 1; off < 256; off <<= 1){
    int u = (t >= off) ? pre[t - off] : 0;
    __syncthreads();
    pre[t] += u;
    __syncthreads();
  }
  int excl = pre[t] - v;                         // exclusive scan
  int d = r * 256 + t;
  if(d < N_NODES) rp[d] = beg + excl;
  if(r == NRANGES - 1 && t == 0) rp[N_NODES] = N_EDGES;
  __syncthreads();
  cnt[t] = beg + excl;                           // reuse as cursors
  __syncthreads();
  for(int i = beg + t; i < end; i += 256){
    int2 e = staged[i];
    int dl = (e.y >> 16) & 255;
    int p = atomicAdd(&cnt[dl], 1);
    epack[p] = make_int2(e.x, e.y & 0xffff);
  }
}

// ---------------- weight prep: frag-ordered bf16 tables ----------------
// b_frag convention: lane l holds B[k = ks*32 + (l>>4)*8 + i][c = nf*16 + (l&15)]

__global__ void k_prepW(const float* __restrict__ W1, const float* __restrict__ W2,
                        __bf16* __restrict__ W1f, __bf16* __restrict__ W2f){
  int t = blockIdx.x * 256 + threadIdx.x;
  if(t < 4096){
    int ks = t >> 9, rem = t & 511, nf = rem >> 6, l = rem & 63;
    int k = ks * 32 + (l >> 4) * 8, c = nf * 16 + (l & 15);
    bf16x8 v;
    #pragma unroll
    for(int i = 0; i < 8; i++) v[i] = (__bf16)W1[(size_t)(k + i) * HID + c];
    *(bf16x8*)(W1f + ((size_t)t << 3)) = v;
  } else if(t < 6144){
    int s = t - 4096;
    int ks = s >> 9, rem = s & 511, nf = rem >> 6, l = rem & 63;
    int k = ks * 32 + (l >> 4) * 8, c = nf * 16 + (l & 15);
    bf16x8 v;
    #pragma unroll
    for(int i = 0; i < 8; i++){
      int kk = k + i;
      float val = (c < 64) ? W2[(size_t)kk * F_OUT + c]
                           : W2[(size_t)(HID + kk) * F_OUT + (c - 64)];
      v[i] = (__bf16)val;
    }
    *(bf16x8*)(W2f + ((size_t)s << 3)) = v;
  }
}

// ---------------- X -> bf16 plane Sx [N][128] ----------------

__global__ __launch_bounds__(256) void k_cvtX(const float* __restrict__ X, __bf16* __restrict__ Sx){
  int t = blockIdx.x * 256 + threadIdx.x;
  if(t >= N_NODES * 16) return;
  int n = t >> 4;
  int c = (t & 15) * 8;
  const float* xp = X + (size_t)n * F_IN + c;
  f32x4 x0 = *(const f32x4*)xp;
  f32x4 x1 = *(const f32x4*)(xp + 4);
  bf16x8 v;
  #pragma unroll
  for(int i = 0; i < 4; i++){ v[i] = (__bf16)x0[i]; v[4 + i] = (__bf16)x1[i]; }
  *(bf16x8*)(Sx + (size_t)n * 128 + c) = v;
}

// ---------------- SpMM 1: Sa[w] = sum_e w_e * Sx[src_e]  (bf16, 128-wide, 4-edge ILP) ----------------

__global__ __launch_bounds__(256) void k_spmm1(const __bf16* __restrict__ Sx,
    __bf16* __restrict__ Sa, const int2* __restrict__ epack, const int* __restrict__ rp){
  int w    = (int)((blockIdx.x * blockDim.x + threadIdx.x) >> 6);
  int lane = threadIdx.x & 63;
  if(w >= N_NODES) return;
  int beg = rp[w], end = rp[w + 1];
  float a0 = 0.f, a1 = 0.f;
  int e = beg;
  for(; e + 3 < end; e += 4){
    int2 p0 = epack[e], p1 = epack[e + 1], p2 = epack[e + 2], p3 = epack[e + 3];
    unsigned u0 = *(const unsigned*)(Sx + (size_t)p0.y * 128 + lane * 2);
    unsigned u1 = *(const unsigned*)(Sx + (size_t)p1.y * 128 + lane * 2);
    unsigned u2 = *(const unsigned*)(Sx + (size_t)p2.y * 128 + lane * 2);
    unsigned u3 = *(const unsigned*)(Sx + (size_t)p3.y * 128 + lane * 2);
    float w0 = __int_as_float(p0.x), w1 = __int_as_float(p1.x);
    float w2 = __int_as_float(p2.x), w3 = __int_as_float(p3.x);
    a0 = fmaf(w0, bflo(u0), a0); a1 = fmaf(w0, bfhi(u0), a1);
    a0 = fmaf(w1, bflo(u1), a0); a1 = fmaf(w1, bfhi(u1), a1);
    a0 = fmaf(w2, bflo(u2), a0); a1 = fmaf(w2, bfhi(u2), a1);
    a0 = fmaf(w3, bflo(u3), a0); a1 = fmaf(w3, bfhi(u3), a1);
  }
  for(; e < end; e++){
    int2 p = epack[e];
    float wt = __int_as_float(p.x);
    unsigned u = *(const unsigned*)(Sx + (size_t)p.y * 128 + lane * 2);
    a0 = fmaf(wt, bflo(u), a0); a1 = fmaf(wt, bfhi(u), a1);
  }
  *(unsigned*)(Sa + (size_t)w * 128 + lane * 2) = packbf(a0, a1);
}

// ---------------- GEMM 1 (MFMA): h_pre(bf16) = [Sa|Sx] @ W1 + b1, + BN partials ----------------

__global__ __launch_bounds__(256) void k_gemm1(
    const __bf16* __restrict__ Sa, const __bf16* __restrict__ Sx,
    const __bf16* __restrict__ W1f, const float* __restrict__ b1,
    __bf16* __restrict__ hpre, float* __restrict__ bn_acc){
  __shared__ float bnred[2][256];
  const int tid = threadIdx.x;
  const int lane = tid & 63, wid = tid >> 6;
  const int wm = wid >> 1, wn = wid & 1;
  const int lr = lane & 15, lk = (lane >> 4) * 8;
  const int rbase = blockIdx.x * 64 + wm * 32 + lr;

  f32x4 acc[2][4];
  #pragma unroll
  for(int m = 0; m < 2; m++)
    #pragma unroll
    for(int n = 0; n < 4; n++) acc[m][n] = (f32x4){0.f, 0.f, 0.f, 0.f};

  for(int ks = 0; ks < 8; ks++){
    const __bf16* src = (ks < 4) ? Sa : Sx;
    const int kb = (ks & 3) * 32 + lk;
    bf16x8 a[2], b[4];
    #pragma unroll
    for(int m = 0; m < 2; m++){
      int r = rbase + m * 16; if(r > N_NODES - 1) r = N_NODES - 1;
      a[m] = *(const bf16x8*)(src + (size_t)r * 128 + kb);
    }
    #pragma unroll
    for(int n = 0; n < 4; n++)
      b[n] = *(const bf16x8*)(W1f + (((ks * 8 + wn * 4 + n) * 64 + lane) << 3));
    #pragma unroll
    for(int m = 0; m < 2; m++)
      #pragma unroll
      for(int n = 0; n < 4; n++)
        acc[m][n] = __builtin_amdgcn_mfma_f32_16x16x32_bf16(a[m], b[n], acc[m][n], 0, 0, 0);
  }

  #pragma unroll
  for(int n = 0; n < 4; n++){
    int gc = wn * 64 + n * 16 + lr;
    float bias = b1[gc];
    float ps = 0.f, pq = 0.f;
    #pragma unroll
    for(int m = 0; m < 2; m++){
      int gr0 = blockIdx.x * 64 + wm * 32 + m * 16 + (lane >> 4) * 4;
      #pragma unroll
      for(int i = 0; i < 4; i++){
        int r = gr0 + i;
        if(r < N_NODES){
          float h = acc[m][n][i] + bias;
          hpre[(size_t)r * HID + gc] = (__bf16)h;
          ps += h; pq += h * h;
        }
      }
    }
    ps += __shfl_xor(ps, 16); ps += __shfl_xor(ps, 32);
    pq += __shfl_xor(pq, 16); pq += __shfl_xor(pq, 32);
    if(lane < 16){
      bnred[wm][gc] = ps;
      bnred[wm][128 + gc] = pq;
    }
  }
  __syncthreads();
  atomicAdd(&bn_acc[tid], bnred[0][tid] + bnred[1][tid]);
}

// ---------------- BN stats ----------------

__global__ void k_bnstats(const float* __restrict__ bn_acc, const float* __restrict__ gamma,
                          const float* __restrict__ beta, float* __restrict__ bn_sc){
  int c = threadIdx.x;
  if(c < HID){
    float mean = bn_acc[c] / (float)N_NODES;
    float var  = bn_acc[HID + c] / (float)N_NODES - mean * mean;
    float rs   = rsqrtf(var + BN_EPS);
    float sc   = gamma[c] * rs;
    bn_sc[c]       = sc;
    bn_sc[HID + c] = beta[c] - mean * sc;
  }
}

// ---------------- GEMM 2 (MFMA): BN+ReLU fused into A-frags ----------------

__global__ __launch_bounds__(256) void k_gemm2(
    const __bf16* __restrict__ hpre, const __bf16* __restrict__ W2f,
    const float* __restrict__ b2, const float* __restrict__ bn_sc,
    __bf16* __restrict__ y2b, float* __restrict__ out){
  const int tid = threadIdx.x;
  const int lane = tid & 63, wid = tid >> 6;
  const int wm = wid >> 1, wn = wid & 1;
  const int lr = lane & 15, lk = (lane >> 4) * 8;
  const int rbase = blockIdx.x * 64 + wm * 32 + lr;

  f32x4 acc[2][4];
  #pragma unroll
  for(int m = 0; m < 2; m++)
    #pragma unroll
    for(int n = 0; n < 4; n++) acc[m][n] = (f32x4){0.f, 0.f, 0.f, 0.f};

  for(int ks = 0; ks < 4; ks++){
    int k0 = ks * 32 + lk;
    f32x4 sc0 = *(const f32x4*)(bn_sc + k0);
    f32x4 sc1 = *(const f32x4*)(bn_sc + k0 + 4);
    f32x4 sh0 = *(const f32x4*)(bn_sc + 128 + k0);
    f32x4 sh1 = *(const f32x4*)(bn_sc + 128 + k0 + 4);
    bf16x8 a[2], b[4];
    #pragma unroll
    for(int m = 0; m < 2; m++){
      int r = rbase + m * 16; if(r > N_NODES - 1) r = N_NODES - 1;
      bf16x8 hv = *(const bf16x8*)(hpre + (size_t)r * HID + k0);
      bf16x8 af;
      #pragma unroll
      for(int i = 0; i < 4; i++){
        af[i]     = (__bf16)fmaxf(0.f, fmaf((float)hv[i],     sc0[i], sh0[i]));
        af[4 + i] = (__bf16)fmaxf(0.f, fmaf((float)hv[4 + i], sc1[i], sh1[i]));
      }
      a[m] = af;
    }
    #pragma unroll
    for(int n = 0; n < 4; n++)
      b[n] = *(const bf16x8*)(W2f + (((ks * 8 + wn * 4 + n) * 64 + lane) << 3));
    #pragma unroll
    for(int m = 0; m < 2; m++)
      #pragma unroll
      for(int n = 0; n < 4; n++)
        acc[m][n] = __builtin_amdgcn_mfma_f32_16x16x32_bf16(a[m], b[n], acc[m][n], 0, 0, 0);
  }

  #pragma unroll
  for(int n = 0; n < 4; n++){
    int c = n * 16 + lr;
    float bias = (wn == 1) ? b2[c] : 0.f;
    #pragma unroll
    for(int m = 0; m < 2; m++){
      int gr0 = blockIdx.x * 64 + wm * 32 + m * 16 + (lane >> 4) * 4;
      #pragma unroll
      for(int i = 0; i < 4; i++){
        int r = gr0 + i;
        if(r < N_NODES){
          if(wn == 0) y2b[(size_t)r * F_OUT + c] = (__bf16)acc[m][n][i];
          else        out[(size_t)r * F_OUT + c] = acc[m][n][i] + bias;
        }
      }
    }
  }
}

// ---------------- SpMM 2: out += A @ y2 (bf16 gather, 2x2 edges per wave-iter) ----------------

__global__ __launch_bounds__(256) void k_spmm2(const __bf16* __restrict__ y2b,
    const int2* __restrict__ epack, const int* __restrict__ rp, float* __restrict__ out){
  int w    = (int)((blockIdx.x * blockDim.x + threadIdx.x) >> 6);
  int lane = threadIdx.x & 63;
  if(w >= N_NODES) return;
  int beg = rp[w], end = rp[w + 1];
  int half = lane >> 5, li = lane & 31;
  float a0 = 0.f, a1 = 0.f;
  int e = beg + half;
  for(; e + 2 < end; e += 4){
    int2 p0 = epack[e], p1 = epack[e + 2];
    float w0 = __int_as_float(p0.x), w1 = __int_as_float(p1.x);
    unsigned u0 = *(const unsigned*)(y2b + (size_t)p0.y * F_OUT + li * 2);
    unsigned u1 = *(const unsigned*)(y2b + (size_t)p1.y * F_OUT + li * 2);
    a0 = fmaf(w0, bflo(u0), a0); a1 = fmaf(w0, bfhi(u0), a1);
    a0 = fmaf(w1, bflo(u1), a0); a1 = fmaf(w1, bfhi(u1), a1);
  }
  if(e < end){
    int2 p = epack[e];
    float wt = __int_as_float(p.x);
    unsigned u = *(const unsigned*)(y2b + (size_t)p.y * F_OUT + li * 2);
    a0 = fmaf(wt, bflo(u), a0); a1 = fmaf(wt, bfhi(u), a1);
  }
  a0 += __shfl_xor(a0, 32);
  a1 += __shfl_xor(a1, 32);
  if(lane < 32){
    float2 o = *(float2*)(out + (size_t)w * F_OUT + li * 2);
    o.x += a0; o.y += a1;
    *(float2*)(out + (size_t)w * F_OUT + li * 2) = o;
  }
}

// ---------------- launch ----------------

extern "C" void kernel_launch(void* const* d_in, const int* in_sizes, int n_in,
                              void* d_out, int out_size, void* d_ws, size_t ws_size,
                              hipStream_t stream){
  const float* X     = (const float*)d_in[0];
  const float* W1    = (const float*)d_in[1];
  const float* b1    = (const float*)d_in[2];
  const float* gamma = (const float*)d_in[3];
  const float* beta  = (const float*)d_in[4];
  const float* W2    = (const float*)d_in[5];
  const float* b2    = (const float*)d_in[6];
  const float* evals = (const float*)d_in[7];
  const int*   esrc  = (const int*)d_in[8];
  const int*   edst  = (const int*)d_in[9];
  float* out = (float*)d_out;

  char* ws = (char*)d_ws;
  size_t off = 0;
  auto carve = [&](size_t bytes) -> char* {
    off = align_up(off, 256);
    char* p = ws + off;
    off += bytes;
    return p;
  };
  int*     Hcr    = (int*)    carve((size_t)NCHUNKS * NRANGES * 4);
  int*     rscan  = (int*)    carve((size_t)(NRANGES + 1) * 4);
  int*     rp     = (int*)    carve(((size_t)N_NODES + 1) * 4);
  float*   bn_acc = (float*)  carve(256 * 4);
  float*   bn_sc  = (float*)  carve(256 * 4);
  int2*    staged = (int2*)   carve((size_t)N_EDGES * 8);
  int2*    epack  = (int2*)   carve((size_t)N_EDGES * 8);
  __bf16*  W1f    = (__bf16*) carve((size_t)4096 * 8 * 2);
  __bf16*  W2f    = (__bf16*) carve((size_t)2048 * 8 * 2);
  __bf16*  Sa     = (__bf16*) carve((size_t)N_NODES * 128 * 2);
  __bf16*  Sx     = (__bf16*) carve((size_t)N_NODES * 128 * 2);
  __bf16*  hpre   = (__bf16*) carve((size_t)N_NODES * HID * 2);
  __bf16*  y2b    = (__bf16*) carve((size_t)N_NODES * F_OUT * 2);

  k_pass1<<<NCHUNKS, 256, 0, stream>>>(edst, Hcr);
  k_scanH<<<1, 256, 0, stream>>>(Hcr, rscan, bn_acc);
  k_pass2<<<NCHUNKS, 256, 0, stream>>>(edst, esrc, evals, Hcr, rscan, staged);
  k_pass3<<<NRANGES, 256, 0, stream>>>(staged, rscan, epack, rp);

  k_prepW<<<24, 256, 0, stream>>>(W1, W2, W1f, W2f);
  k_cvtX<<<(N_NODES * 16 + 255) / 256, 256, 0, stream>>>(X, Sx);

  k_spmm1<<<N_NODES / 4, 256, 0, stream>>>(Sx, Sa, epack, rp);
  k_gemm1<<<(N_NODES + 63) / 64, 256, 0, stream>>>(Sa, Sx, W1f, b1, hpre, bn_acc);
  k_bnstats<<<1, 128, 0, stream>>>(bn_acc, gamma, beta, bn_sc);
  k_gemm2<<<(N_NODES + 63) / 64, 256, 0, stream>>>(hpre, W2f, b2, bn_sc, y2b, out);
  k_spmm2<<<N_NODES / 4, 256, 0, stream>>>(y2b, epack, rp, out);
}

// Round 5
// 245.705 us; speedup vs baseline: 1.7285x; 1.0406x over previous
//
#include <hip/hip_runtime.h>

#define N_NODES 50000
#define N_EDGES 800000
#define F_IN    128
#define HID     128
#define F_OUT   64
#define BN_EPS  1e-5f

#define NRANGES 196          // dst ranges of 256 nodes: ceil(50000/256)
#define NCHUNKS 196          // edge chunks of 4096: ceil(800000/4096)
#define CHUNK   4096
#define CVT_BLOCKS 3125      // 800000 / 256
#define PREPW_BLOCKS 24      // 6144 / 256

typedef __bf16 bf16x8 __attribute__((ext_vector_type(8)));
typedef float  f32x4  __attribute__((ext_vector_type(4)));

static inline size_t align_up(size_t x, size_t a){ return (x + a - 1) / a * a; }

__device__ __forceinline__ float bflo(unsigned u){ return __uint_as_float(u << 16); }
__device__ __forceinline__ float bfhi(unsigned u){ return __uint_as_float(u & 0xffff0000u); }
__device__ __forceinline__ unsigned packbf(float a, float b){
  __bf16 ha = (__bf16)a, hb = (__bf16)b;
  unsigned short ua = __builtin_bit_cast(unsigned short, ha);
  unsigned short ub = __builtin_bit_cast(unsigned short, hb);
  return (unsigned)ua | ((unsigned)ub << 16);
}

// ---------------- setup: pass1-hist || cvtX || prepW || zero bn_acc ----------------
// b_frag convention: lane l holds B[k = ks*32 + (l>>4)*8 + i][c = nf*16 + (l&15)]

__global__ __launch_bounds__(256) void k_setup(
    const int* __restrict__ dst, const float* __restrict__ X,
    const float* __restrict__ W1, const float* __restrict__ W2,
    int* __restrict__ Hcr, __bf16* __restrict__ Sx,
    __bf16* __restrict__ W1f, __bf16* __restrict__ W2f, float* __restrict__ bn_acc){
  __shared__ int hist[NRANGES];
  int b = blockIdx.x, t = threadIdx.x;
  if(b < NCHUNKS){
    // per-chunk histogram over dst ranges (LDS atomics only)
    if(t < NRANGES) hist[t] = 0;
    __syncthreads();
    int e0 = b * CHUNK;
    #pragma unroll
    for(int k = 0; k < CHUNK / 256; k++){
      int e = e0 + k * 256 + t;
      if(e < N_EDGES) atomicAdd(&hist[dst[e] >> 8], 1);
    }
    __syncthreads();
    if(t < NRANGES) Hcr[b * NRANGES + t] = hist[t];
  } else if(b < NCHUNKS + CVT_BLOCKS){
    int bb = b - NCHUNKS;
    if(bb == 0) bn_acc[t] = 0.f;
    int idx = bb * 256 + t;                    // < 800000
    int n = idx >> 4;
    int c = (idx & 15) * 8;
    const float* xp = X + (size_t)n * F_IN + c;
    f32x4 x0 = *(const f32x4*)xp;
    f32x4 x1 = *(const f32x4*)(xp + 4);
    bf16x8 v;
    #pragma unroll
    for(int i = 0; i < 4; i++){ v[i] = (__bf16)x0[i]; v[4 + i] = (__bf16)x1[i]; }
    *(bf16x8*)(Sx + (size_t)n * 128 + c) = v;
  } else {
    int s = (b - NCHUNKS - CVT_BLOCKS) * 256 + t;   // 0..6143
    if(s < 4096){
      int ks = s >> 9, rem = s & 511, nf = rem >> 6, l = rem & 63;
      int k = ks * 32 + (l >> 4) * 8, c = nf * 16 + (l & 15);
      bf16x8 v;
      #pragma unroll
      for(int i = 0; i < 8; i++) v[i] = (__bf16)W1[(size_t)(k + i) * HID + c];
      *(bf16x8*)(W1f + ((size_t)s << 3)) = v;
    } else {
      int q = s - 4096;
      int ks = q >> 9, rem = q & 511, nf = rem >> 6, l = rem & 63;
      int k = ks * 32 + (l >> 4) * 8, c = nf * 16 + (l & 15);
      bf16x8 v;
      #pragma unroll
      for(int i = 0; i < 8; i++){
        int kk = k + i;
        float val = (c < 64) ? W2[(size_t)kk * F_OUT + c]
                             : W2[(size_t)(HID + kk) * F_OUT + (c - 64)];
        v[i] = (__bf16)val;
      }
      *(bf16x8*)(W2f + ((size_t)q << 3)) = v;
    }
  }
}

// ---------------- scanR: per-range exclusive scan over chunks (196 parallel blocks) ----------------

__global__ __launch_bounds__(256) void k_scanR(int* __restrict__ Hcr, int* __restrict__ rtot){
  __shared__ int s[256];
  int r = blockIdx.x, t = threadIdx.x;
  int v = (t < NCHUNKS) ? Hcr[t * NRANGES + r] : 0;
  s[t] = v;
  __syncthreads();
  for(int off = 1; off < 256; off <<= 1){
    int u = (t >= off) ? s[t - off] : 0;
    __syncthreads();
    s[t] += u;
    __syncthreads();
  }
  if(t < NCHUNKS) Hcr[t * NRANGES + r] = s[t] - v;   // exclusive over chunks
  if(t == NCHUNKS - 1) rtot[r] = s[t];               // range total
}

// ---------------- pass2: place edges into range-grouped staging (exact disjoint slots) ----------------
// staged.y = src | (d&255) << 16

__global__ __launch_bounds__(256) void k_pass2(const int* __restrict__ dst, const int* __restrict__ src,
    const float* __restrict__ vals, const int* __restrict__ Hcr,
    const int* __restrict__ rtot, int2* __restrict__ staged){
  __shared__ int s[256];
  __shared__ int cur[NRANGES];
  int c = blockIdx.x, t = threadIdx.x;
  int tv = (t < NRANGES) ? rtot[t] : 0;
  s[t] = tv;
  __syncthreads();
  for(int off = 1; off < 256; off <<= 1){
    int u = (t >= off) ? s[t - off] : 0;
    __syncthreads();
    s[t] += u;
    __syncthreads();
  }
  if(t < NRANGES) cur[t] = (s[t] - tv) + Hcr[c * NRANGES + t];
  __syncthreads();
  int e0 = c * CHUNK;
  #pragma unroll
  for(int k = 0; k < CHUNK / 256; k++){
    int e = e0 + k * 256 + t;
    if(e < N_EDGES){
      int d = dst[e];
      int pos = atomicAdd(&cur[d >> 8], 1);      // LDS atomic
      staged[pos] = make_int2(__float_as_int(vals[e]), src[e] | ((d & 255) << 16));
    }
  }
}

// ---------------- pass3: one wg owns range r: write rp[] + final dst-sorted epack ----------------

__global__ __launch_bounds__(256) void k_pass3(const int2* __restrict__ staged,
    const int* __restrict__ rtot, int2* __restrict__ epack, int* __restrict__ rp){
  __shared__ int s[256];
  __shared__ int cnt[256];
  __shared__ int begS, endS;
  int r = blockIdx.x, t = threadIdx.x;
  int tv = (t < NRANGES) ? rtot[t] : 0;
  s[t] = tv;
  __syncthreads();
  for(int off = 1; off < 256; off <<= 1){
    int u = (t >= off) ? s[t - off] : 0;
    __syncthreads();
    s[t] += u;
    __syncthreads();
  }
  if(t == r){ begS = s[t] - tv; endS = s[t]; }
  cnt[t] = 0;
  __syncthreads();
  int beg = begS, end = endS;
  for(int i = beg + t; i < end; i += 256)
    atomicAdd(&cnt[(staged[i].y >> 16) & 255], 1);
  __syncthreads();
  int v = cnt[t];
  s[t] = v;
  __syncthreads();
  for(int off = 1; off < 256; off <<= 1){
    int u = (t >= off) ? s[t - off] : 0;
    __syncthreads();
    s[t] += u;
    __syncthreads();
  }
  int excl = s[t] - v;
  int d = r * 256 + t;
  if(d < N_NODES) rp[d] = beg + excl;
  if(r == NRANGES - 1 && t == 0) rp[N_NODES] = N_EDGES;
  __syncthreads();
  cnt[t] = beg + excl;                           // reuse as cursors
  __syncthreads();
  for(int i = beg + t; i < end; i += 256){
    int2 e = staged[i];
    int dl = (e.y >> 16) & 255;
    int p = atomicAdd(&cnt[dl], 1);
    epack[p] = make_int2(e.x, e.y & 0xffff);
  }
}

// ---------------- SpMM 1: Sa[w] = sum_e w_e * Sx[src_e]  (bf16, 128-wide, 4-edge ILP) ----------------

__global__ __launch_bounds__(256) void k_spmm1(const __bf16* __restrict__ Sx,
    __bf16* __restrict__ Sa, const int2* __restrict__ epack, const int* __restrict__ rp){
  int w    = (int)((blockIdx.x * blockDim.x + threadIdx.x) >> 6);
  int lane = threadIdx.x & 63;
  if(w >= N_NODES) return;
  int beg = rp[w], end = rp[w + 1];
  float a0 = 0.f, a1 = 0.f;
  int e = beg;
  for(; e + 3 < end; e += 4){
    int2 p0 = epack[e], p1 = epack[e + 1], p2 = epack[e + 2], p3 = epack[e + 3];
    unsigned u0 = *(const unsigned*)(Sx + (size_t)p0.y * 128 + lane * 2);
    unsigned u1 = *(const unsigned*)(Sx + (size_t)p1.y * 128 + lane * 2);
    unsigned u2 = *(const unsigned*)(Sx + (size_t)p2.y * 128 + lane * 2);
    unsigned u3 = *(const unsigned*)(Sx + (size_t)p3.y * 128 + lane * 2);
    float w0 = __int_as_float(p0.x), w1 = __int_as_float(p1.x);
    float w2 = __int_as_float(p2.x), w3 = __int_as_float(p3.x);
    a0 = fmaf(w0, bflo(u0), a0); a1 = fmaf(w0, bfhi(u0), a1);
    a0 = fmaf(w1, bflo(u1), a0); a1 = fmaf(w1, bfhi(u1), a1);
    a0 = fmaf(w2, bflo(u2), a0); a1 = fmaf(w2, bfhi(u2), a1);
    a0 = fmaf(w3, bflo(u3), a0); a1 = fmaf(w3, bfhi(u3), a1);
  }
  for(; e < end; e++){
    int2 p = epack[e];
    float wt = __int_as_float(p.x);
    unsigned u = *(const unsigned*)(Sx + (size_t)p.y * 128 + lane * 2);
    a0 = fmaf(wt, bflo(u), a0); a1 = fmaf(wt, bfhi(u), a1);
  }
  *(unsigned*)(Sa + (size_t)w * 128 + lane * 2) = packbf(a0, a1);
}

// ---------------- GEMM 1 (MFMA): h_pre(bf16) = [Sa|Sx] @ W1 + b1, + BN partials ----------------

__global__ __launch_bounds__(256) void k_gemm1(
    const __bf16* __restrict__ Sa, const __bf16* __restrict__ Sx,
    const __bf16* __restrict__ W1f, const float* __restrict__ b1,
    __bf16* __restrict__ hpre, float* __restrict__ bn_acc){
  __shared__ float bnred[2][256];
  const int tid = threadIdx.x;
  const int lane = tid & 63, wid = tid >> 6;
  const int wm = wid >> 1, wn = wid & 1;
  const int lr = lane & 15, lk = (lane >> 4) * 8;
  const int rbase = blockIdx.x * 64 + wm * 32 + lr;

  f32x4 acc[2][4];
  #pragma unroll
  for(int m = 0; m < 2; m++)
    #pragma unroll
    for(int n = 0; n < 4; n++) acc[m][n] = (f32x4){0.f, 0.f, 0.f, 0.f};

  for(int ks = 0; ks < 8; ks++){
    const __bf16* src = (ks < 4) ? Sa : Sx;
    const int kb = (ks & 3) * 32 + lk;
    bf16x8 a[2], b[4];
    #pragma unroll
    for(int m = 0; m < 2; m++){
      int r = rbase + m * 16; if(r > N_NODES - 1) r = N_NODES - 1;
      a[m] = *(const bf16x8*)(src + (size_t)r * 128 + kb);
    }
    #pragma unroll
    for(int n = 0; n < 4; n++)
      b[n] = *(const bf16x8*)(W1f + (((ks * 8 + wn * 4 + n) * 64 + lane) << 3));
    #pragma unroll
    for(int m = 0; m < 2; m++)
      #pragma unroll
      for(int n = 0; n < 4; n++)
        acc[m][n] = __builtin_amdgcn_mfma_f32_16x16x32_bf16(a[m], b[n], acc[m][n], 0, 0, 0);
  }

  #pragma unroll
  for(int n = 0; n < 4; n++){
    int gc = wn * 64 + n * 16 + lr;
    float bias = b1[gc];
    float ps = 0.f, pq = 0.f;
    #pragma unroll
    for(int m = 0; m < 2; m++){
      int gr0 = blockIdx.x * 64 + wm * 32 + m * 16 + (lane >> 4) * 4;
      #pragma unroll
      for(int i = 0; i < 4; i++){
        int r = gr0 + i;
        if(r < N_NODES){
          float h = acc[m][n][i] + bias;
          hpre[(size_t)r * HID + gc] = (__bf16)h;
          ps += h; pq += h * h;
        }
      }
    }
    ps += __shfl_xor(ps, 16); ps += __shfl_xor(ps, 32);
    pq += __shfl_xor(pq, 16); pq += __shfl_xor(pq, 32);
    if(lane < 16){
      bnred[wm][gc] = ps;
      bnred[wm][128 + gc] = pq;
    }
  }
  __syncthreads();
  atomicAdd(&bn_acc[tid], bnred[0][tid] + bnred[1][tid]);
}

// ---------------- GEMM 2 (MFMA): BN stats inline; BN+ReLU fused into A-frags ----------------

__global__ __launch_bounds__(256) void k_gemm2(
    const __bf16* __restrict__ hpre, const __bf16* __restrict__ W2f,
    const float* __restrict__ b2, const float* __restrict__ bn_acc,
    const float* __restrict__ gamma, const float* __restrict__ beta,
    __bf16* __restrict__ y2b, float* __restrict__ out){
  __shared__ float s_scale[HID], s_shift[HID];
  const int tid = threadIdx.x;
  if(tid < HID){
    float mean = bn_acc[tid] / (float)N_NODES;
    float var  = bn_acc[HID + tid] / (float)N_NODES - mean * mean;
    float rs   = rsqrtf(var + BN_EPS);
    float sc   = gamma[tid] * rs;
    s_scale[tid] = sc;
    s_shift[tid] = beta[tid] - mean * sc;
  }
  const int lane = tid & 63, wid = tid >> 6;
  const int wm = wid >> 1, wn = wid & 1;
  const int lr = lane & 15, lk = (lane >> 4) * 8;
  const int rbase = blockIdx.x * 64 + wm * 32 + lr;

  f32x4 acc[2][4];
  #pragma unroll
  for(int m = 0; m < 2; m++)
    #pragma unroll
    for(int n = 0; n < 4; n++) acc[m][n] = (f32x4){0.f, 0.f, 0.f, 0.f};
  __syncthreads();

  for(int ks = 0; ks < 4; ks++){
    int k0 = ks * 32 + lk;
    f32x4 sc0 = *(const f32x4*)(s_scale + k0);
    f32x4 sc1 = *(const f32x4*)(s_scale + k0 + 4);
    f32x4 sh0 = *(const f32x4*)(s_shift + k0);
    f32x4 sh1 = *(const f32x4*)(s_shift + k0 + 4);
    bf16x8 a[2], b[4];
    #pragma unroll
    for(int m = 0; m < 2; m++){
      int r = rbase + m * 16; if(r > N_NODES - 1) r = N_NODES - 1;
      bf16x8 hv = *(const bf16x8*)(hpre + (size_t)r * HID + k0);
      bf16x8 af;
      #pragma unroll
      for(int i = 0; i < 4; i++){
        af[i]     = (__bf16)fmaxf(0.f, fmaf((float)hv[i],     sc0[i], sh0[i]));
        af[4 + i] = (__bf16)fmaxf(0.f, fmaf((float)hv[4 + i], sc1[i], sh1[i]));
      }
      a[m] = af;
    }
    #pragma unroll
    for(int n = 0; n < 4; n++)
      b[n] = *(const bf16x8*)(W2f + (((ks * 8 + wn * 4 + n) * 64 + lane) << 3));
    #pragma unroll
    for(int m = 0; m < 2; m++)
      #pragma unroll
      for(int n = 0; n < 4; n++)
        acc[m][n] = __builtin_amdgcn_mfma_f32_16x16x32_bf16(a[m], b[n], acc[m][n], 0, 0, 0);
  }

  #pragma unroll
  for(int n = 0; n < 4; n++){
    int c = n * 16 + lr;
    float bias = (wn == 1) ? b2[c] : 0.f;
    #pragma unroll
    for(int m = 0; m < 2; m++){
      int gr0 = blockIdx.x * 64 + wm * 32 + m * 16 + (lane >> 4) * 4;
      #pragma unroll
      for(int i = 0; i < 4; i++){
        int r = gr0 + i;
        if(r < N_NODES){
          if(wn == 0) y2b[(size_t)r * F_OUT + c] = (__bf16)acc[m][n][i];
          else        out[(size_t)r * F_OUT + c] = acc[m][n][i] + bias;
        }
      }
    }
  }
}

// ---------------- SpMM 2: out += A @ y2 (bf16 gather, 2x2 edges per wave-iter) ----------------

__global__ __launch_bounds__(256) void k_spmm2(const __bf16* __restrict__ y2b,
    const int2* __restrict__ epack, const int* __restrict__ rp, float* __restrict__ out){
  int w    = (int)((blockIdx.x * blockDim.x + threadIdx.x) >> 6);
  int lane = threadIdx.x & 63;
  if(w >= N_NODES) return;
  int beg = rp[w], end = rp[w + 1];
  int half = lane >> 5, li = lane & 31;
  float a0 = 0.f, a1 = 0.f;
  int e = beg + half;
  for(; e + 2 < end; e += 4){
    int2 p0 = epack[e], p1 = epack[e + 2];
    float w0 = __int_as_float(p0.x), w1 = __int_as_float(p1.x);
    unsigned u0 = *(const unsigned*)(y2b + (size_t)p0.y * F_OUT + li * 2);
    unsigned u1 = *(const unsigned*)(y2b + (size_t)p1.y * F_OUT + li * 2);
    a0 = fmaf(w0, bflo(u0), a0); a1 = fmaf(w0, bfhi(u0), a1);
    a0 = fmaf(w1, bflo(u1), a0); a1 = fmaf(w1, bfhi(u1), a1);
  }
  if(e < end){
    int2 p = epack[e];
    float wt = __int_as_float(p.x);
    unsigned u = *(const unsigned*)(y2b + (size_t)p.y * F_OUT + li * 2);
    a0 = fmaf(wt, bflo(u), a0); a1 = fmaf(wt, bfhi(u), a1);
  }
  a0 += __shfl_xor(a0, 32);
  a1 += __shfl_xor(a1, 32);
  if(lane < 32){
    float2 o = *(float2*)(out + (size_t)w * F_OUT + li * 2);
    o.x += a0; o.y += a1;
    *(float2*)(out + (size_t)w * F_OUT + li * 2) = o;
  }
}

// ---------------- launch ----------------

extern "C" void kernel_launch(void* const* d_in, const int* in_sizes, int n_in,
                              void* d_out, int out_size, void* d_ws, size_t ws_size,
                              hipStream_t stream){
  const float* X     = (const float*)d_in[0];
  const float* W1    = (const float*)d_in[1];
  const float* b1    = (const float*)d_in[2];
  const float* gamma = (const float*)d_in[3];
  const float* beta  = (const float*)d_in[4];
  const float* W2    = (const float*)d_in[5];
  const float* b2    = (const float*)d_in[6];
  const float* evals = (const float*)d_in[7];
  const int*   esrc  = (const int*)d_in[8];
  const int*   edst  = (const int*)d_in[9];
  float* out = (float*)d_out;

  char* ws = (char*)d_ws;
  size_t off = 0;
  auto carve = [&](size_t bytes) -> char* {
    off = align_up(off, 256);
    char* p = ws + off;
    off += bytes;
    return p;
  };
  int*     Hcr    = (int*)    carve((size_t)NCHUNKS * NRANGES * 4);
  int*     rtot   = (int*)    carve((size_t)NRANGES * 4);
  int*     rp     = (int*)    carve(((size_t)N_NODES + 1) * 4);
  float*   bn_acc = (float*)  carve(256 * 4);
  int2*    staged = (int2*)   carve((size_t)N_EDGES * 8);
  int2*    epack  = (int2*)   carve((size_t)N_EDGES * 8);
  __bf16*  W1f    = (__bf16*) carve((size_t)4096 * 8 * 2);
  __bf16*  W2f    = (__bf16*) carve((size_t)2048 * 8 * 2);
  __bf16*  Sa     = (__bf16*) carve((size_t)N_NODES * 128 * 2);
  __bf16*  Sx     = (__bf16*) carve((size_t)N_NODES * 128 * 2);
  __bf16*  hpre   = (__bf16*) carve((size_t)N_NODES * HID * 2);
  __bf16*  y2b    = (__bf16*) carve((size_t)N_NODES * F_OUT * 2);

  k_setup<<<NCHUNKS + CVT_BLOCKS + PREPW_BLOCKS, 256, 0, stream>>>(
      edst, X, W1, W2, Hcr, Sx, W1f, W2f, bn_acc);
  k_scanR<<<NRANGES, 256, 0, stream>>>(Hcr, rtot);
  k_pass2<<<NCHUNKS, 256, 0, stream>>>(edst, esrc, evals, Hcr, rtot, staged);
  k_pass3<<<NRANGES, 256, 0, stream>>>(staged, rtot, epack, rp);

  k_spmm1<<<N_NODES / 4, 256, 0, stream>>>(Sx, Sa, epack, rp);
  k_gemm1<<<(N_NODES + 63) / 64, 256, 0, stream>>>(Sa, Sx, W1f, b1, hpre, bn_acc);
  k_gemm2<<<(N_NODES + 63) / 64, 256, 0, stream>>>(hpre, W2f, b2, bn_acc, gamma, beta, y2b, out);
  k_spmm2<<<N_NODES / 4, 256, 0, stream>>>(y2b, epack, rp, out);
}

// Round 6
// 232.509 us; speedup vs baseline: 1.8266x; 1.0568x over previous
//
#include <hip/hip_runtime.h>

#define N_NODES 50000
#define N_EDGES 800000
#define F_IN    128
#define HID     128
#define F_OUT   64
#define BN_EPS  1e-5f

#define NRANGES 196          // dst ranges of 256 nodes: ceil(50000/256)
#define NCHUNKS 196          // edge chunks of 4096: ceil(800000/4096)
#define CHUNK   4096
#define CVT_BLOCKS 3125      // 800000 / 256
#define PREPW_BLOCKS 24      // 6144 / 256

typedef __bf16 bf16x8 __attribute__((ext_vector_type(8)));
typedef float  f32x4  __attribute__((ext_vector_type(4)));

static inline size_t align_up(size_t x, size_t a){ return (x + a - 1) / a * a; }

__device__ __forceinline__ float bflo(unsigned u){ return __uint_as_float(u << 16); }
__device__ __forceinline__ float bfhi(unsigned u){ return __uint_as_float(u & 0xffff0000u); }
__device__ __forceinline__ unsigned packbf(float a, float b){
  __bf16 ha = (__bf16)a, hb = (__bf16)b;
  unsigned short ua = __builtin_bit_cast(unsigned short, ha);
  unsigned short ub = __builtin_bit_cast(unsigned short, hb);
  return (unsigned)ua | ((unsigned)ub << 16);
}

// ---------------- setup: pass1-hist || cvtX || prepW || zero bn_acc ----------------
// b_frag convention: lane l holds B[k = ks*32 + (l>>4)*8 + i][c = nf*16 + (l&15)]

__global__ __launch_bounds__(256) void k_setup(
    const int* __restrict__ dst, const float* __restrict__ X,
    const float* __restrict__ W1, const float* __restrict__ W2,
    int* __restrict__ Hcr, __bf16* __restrict__ Sx,
    __bf16* __restrict__ W1f, __bf16* __restrict__ W2f, float* __restrict__ bn_acc){
  __shared__ int hist[NRANGES];
  int b = blockIdx.x, t = threadIdx.x;
  if(b < NCHUNKS){
    // per-chunk histogram over dst ranges (LDS atomics only)
    if(t < NRANGES) hist[t] = 0;
    __syncthreads();
    int e0 = b * CHUNK;
    #pragma unroll
    for(int k = 0; k < CHUNK / 256; k++){
      int e = e0 + k * 256 + t;
      if(e < N_EDGES) atomicAdd(&hist[dst[e] >> 8], 1);
    }
    __syncthreads();
    if(t < NRANGES) Hcr[b * NRANGES + t] = hist[t];
  } else if(b < NCHUNKS + CVT_BLOCKS){
    int bb = b - NCHUNKS;
    if(bb == 0) bn_acc[t] = 0.f;
    int idx = bb * 256 + t;                    // < 800000
    int n = idx >> 4;
    int c = (idx & 15) * 8;
    const float* xp = X + (size_t)n * F_IN + c;
    f32x4 x0 = *(const f32x4*)xp;
    f32x4 x1 = *(const f32x4*)(xp + 4);
    bf16x8 v;
    #pragma unroll
    for(int i = 0; i < 4; i++){ v[i] = (__bf16)x0[i]; v[4 + i] = (__bf16)x1[i]; }
    *(bf16x8*)(Sx + (size_t)n * 128 + c) = v;
  } else {
    int s = (b - NCHUNKS - CVT_BLOCKS) * 256 + t;   // 0..6143
    if(s < 4096){
      int ks = s >> 9, rem = s & 511, nf = rem >> 6, l = rem & 63;
      int k = ks * 32 + (l >> 4) * 8, c = nf * 16 + (l & 15);
      bf16x8 v;
      #pragma unroll
      for(int i = 0; i < 8; i++) v[i] = (__bf16)W1[(size_t)(k + i) * HID + c];
      *(bf16x8*)(W1f + ((size_t)s << 3)) = v;
    } else {
      int q = s - 4096;
      int ks = q >> 9, rem = q & 511, nf = rem >> 6, l = rem & 63;
      int k = ks * 32 + (l >> 4) * 8, c = nf * 16 + (l & 15);
      bf16x8 v;
      #pragma unroll
      for(int i = 0; i < 8; i++){
        int kk = k + i;
        float val = (c < 64) ? W2[(size_t)kk * F_OUT + c]
                             : W2[(size_t)(HID + kk) * F_OUT + (c - 64)];
        v[i] = (__bf16)val;
      }
      *(bf16x8*)(W2f + ((size_t)q << 3)) = v;
    }
  }
}

// ---------------- scanR: per-range exclusive scan over chunks (196 parallel blocks) ----------------

__global__ __launch_bounds__(256) void k_scanR(int* __restrict__ Hcr, int* __restrict__ rtot){
  __shared__ int s[256];
  int r = blockIdx.x, t = threadIdx.x;
  int v = (t < NCHUNKS) ? Hcr[t * NRANGES + r] : 0;
  s[t] = v;
  __syncthreads();
  for(int off = 1; off < 256; off <<= 1){
    int u = (t >= off) ? s[t - off] : 0;
    __syncthreads();
    s[t] += u;
    __syncthreads();
  }
  if(t < NCHUNKS) Hcr[t * NRANGES + r] = s[t] - v;   // exclusive over chunks
  if(t == NCHUNKS - 1) rtot[r] = s[t];               // range total
}

// ---------------- pass2: place edges into range-grouped staging (exact disjoint slots) ----------------
// staged.y = src | (d&255) << 16

__global__ __launch_bounds__(256) void k_pass2(const int* __restrict__ dst, const int* __restrict__ src,
    const float* __restrict__ vals, const int* __restrict__ Hcr,
    const int* __restrict__ rtot, int2* __restrict__ staged){
  __shared__ int s[256];
  __shared__ int cur[NRANGES];
  int c = blockIdx.x, t = threadIdx.x;
  int tv = (t < NRANGES) ? rtot[t] : 0;
  s[t] = tv;
  __syncthreads();
  for(int off = 1; off < 256; off <<= 1){
    int u = (t >= off) ? s[t - off] : 0;
    __syncthreads();
    s[t] += u;
    __syncthreads();
  }
  if(t < NRANGES) cur[t] = (s[t] - tv) + Hcr[c * NRANGES + t];
  __syncthreads();
  int e0 = c * CHUNK;
  #pragma unroll
  for(int k = 0; k < CHUNK / 256; k++){
    int e = e0 + k * 256 + t;
    if(e < N_EDGES){
      int d = dst[e];
      int pos = atomicAdd(&cur[d >> 8], 1);      // LDS atomic
      staged[pos] = make_int2(__float_as_int(vals[e]), src[e] | ((d & 255) << 16));
    }
  }
}

// ---------------- pass3: one wg owns range r: write rp[] + final dst-sorted epack ----------------

__global__ __launch_bounds__(256) void k_pass3(const int2* __restrict__ staged,
    const int* __restrict__ rtot, int2* __restrict__ epack, int* __restrict__ rp){
  __shared__ int s[256];
  __shared__ int cnt[256];
  __shared__ int begS, endS;
  int r = blockIdx.x, t = threadIdx.x;
  int tv = (t < NRANGES) ? rtot[t] : 0;
  s[t] = tv;
  __syncthreads();
  for(int off = 1; off < 256; off <<= 1){
    int u = (t >= off) ? s[t - off] : 0;
    __syncthreads();
    s[t] += u;
    __syncthreads();
  }
  if(t == r){ begS = s[t] - tv; endS = s[t]; }
  cnt[t] = 0;
  __syncthreads();
  int beg = begS, end = endS;
  for(int i = beg + t; i < end; i += 256)
    atomicAdd(&cnt[(staged[i].y >> 16) & 255], 1);
  __syncthreads();
  int v = cnt[t];
  s[t] = v;
  __syncthreads();
  for(int off = 1; off < 256; off <<= 1){
    int u = (t >= off) ? s[t - off] : 0;
    __syncthreads();
    s[t] += u;
    __syncthreads();
  }
  int excl = s[t] - v;
  int d = r * 256 + t;
  if(d < N_NODES) rp[d] = beg + excl;
  if(r == NRANGES - 1 && t == 0) rp[N_NODES] = N_EDGES;
  __syncthreads();
  cnt[t] = beg + excl;                           // reuse as cursors
  __syncthreads();
  for(int i = beg + t; i < end; i += 256){
    int2 e = staged[i];
    int dl = (e.y >> 16) & 255;
    int p = atomicAdd(&cnt[dl], 1);
    epack[p] = make_int2(e.x, e.y & 0xffff);
  }
}

// ---------------- SpMM 1: Sa[w] = sum_e w_e * Sx[src_e]  (bf16, 128-wide, 8-edge MLP) ----------------

__global__ __launch_bounds__(256) void k_spmm1(const __bf16* __restrict__ Sx,
    __bf16* __restrict__ Sa, const int2* __restrict__ epack, const int* __restrict__ rp){
  int w    = (int)((blockIdx.x * blockDim.x + threadIdx.x) >> 6);
  int lane = threadIdx.x & 63;
  if(w >= N_NODES) return;
  int beg = rp[w], end = rp[w + 1];
  float a0 = 0.f, a1 = 0.f;
  int e = beg;
  for(; e + 7 < end; e += 8){
    int2 p0 = epack[e],     p1 = epack[e + 1], p2 = epack[e + 2], p3 = epack[e + 3];
    int2 p4 = epack[e + 4], p5 = epack[e + 5], p6 = epack[e + 6], p7 = epack[e + 7];
    unsigned u0 = *(const unsigned*)(Sx + (size_t)p0.y * 128 + lane * 2);
    unsigned u1 = *(const unsigned*)(Sx + (size_t)p1.y * 128 + lane * 2);
    unsigned u2 = *(const unsigned*)(Sx + (size_t)p2.y * 128 + lane * 2);
    unsigned u3 = *(const unsigned*)(Sx + (size_t)p3.y * 128 + lane * 2);
    unsigned u4 = *(const unsigned*)(Sx + (size_t)p4.y * 128 + lane * 2);
    unsigned u5 = *(const unsigned*)(Sx + (size_t)p5.y * 128 + lane * 2);
    unsigned u6 = *(const unsigned*)(Sx + (size_t)p6.y * 128 + lane * 2);
    unsigned u7 = *(const unsigned*)(Sx + (size_t)p7.y * 128 + lane * 2);
    float w0 = __int_as_float(p0.x), w1 = __int_as_float(p1.x);
    float w2 = __int_as_float(p2.x), w3 = __int_as_float(p3.x);
    float w4 = __int_as_float(p4.x), w5 = __int_as_float(p5.x);
    float w6 = __int_as_float(p6.x), w7 = __int_as_float(p7.x);
    a0 = fmaf(w0, bflo(u0), a0); a1 = fmaf(w0, bfhi(u0), a1);
    a0 = fmaf(w1, bflo(u1), a0); a1 = fmaf(w1, bfhi(u1), a1);
    a0 = fmaf(w2, bflo(u2), a0); a1 = fmaf(w2, bfhi(u2), a1);
    a0 = fmaf(w3, bflo(u3), a0); a1 = fmaf(w3, bfhi(u3), a1);
    a0 = fmaf(w4, bflo(u4), a0); a1 = fmaf(w4, bfhi(u4), a1);
    a0 = fmaf(w5, bflo(u5), a0); a1 = fmaf(w5, bfhi(u5), a1);
    a0 = fmaf(w6, bflo(u6), a0); a1 = fmaf(w6, bfhi(u6), a1);
    a0 = fmaf(w7, bflo(u7), a0); a1 = fmaf(w7, bfhi(u7), a1);
  }
  for(; e + 3 < end; e += 4){
    int2 p0 = epack[e], p1 = epack[e + 1], p2 = epack[e + 2], p3 = epack[e + 3];
    unsigned u0 = *(const unsigned*)(Sx + (size_t)p0.y * 128 + lane * 2);
    unsigned u1 = *(const unsigned*)(Sx + (size_t)p1.y * 128 + lane * 2);
    unsigned u2 = *(const unsigned*)(Sx + (size_t)p2.y * 128 + lane * 2);
    unsigned u3 = *(const unsigned*)(Sx + (size_t)p3.y * 128 + lane * 2);
    float w0 = __int_as_float(p0.x), w1 = __int_as_float(p1.x);
    float w2 = __int_as_float(p2.x), w3 = __int_as_float(p3.x);
    a0 = fmaf(w0, bflo(u0), a0); a1 = fmaf(w0, bfhi(u0), a1);
    a0 = fmaf(w1, bflo(u1), a0); a1 = fmaf(w1, bfhi(u1), a1);
    a0 = fmaf(w2, bflo(u2), a0); a1 = fmaf(w2, bfhi(u2), a1);
    a0 = fmaf(w3, bflo(u3), a0); a1 = fmaf(w3, bfhi(u3), a1);
  }
  for(; e < end; e++){
    int2 p = epack[e];
    float wt = __int_as_float(p.x);
    unsigned u = *(const unsigned*)(Sx + (size_t)p.y * 128 + lane * 2);
    a0 = fmaf(wt, bflo(u), a0); a1 = fmaf(wt, bfhi(u), a1);
  }
  *(unsigned*)(Sa + (size_t)w * 128 + lane * 2) = packbf(a0, a1);
}

// ---------------- GEMM 1 (MFMA): h_pre(bf16) = [Sa|Sx] @ W1 + b1, + BN partials ----------------

__global__ __launch_bounds__(256) void k_gemm1(
    const __bf16* __restrict__ Sa, const __bf16* __restrict__ Sx,
    const __bf16* __restrict__ W1f, const float* __restrict__ b1,
    __bf16* __restrict__ hpre, float* __restrict__ bn_acc){
  __shared__ float bnred[2][256];
  const int tid = threadIdx.x;
  const int lane = tid & 63, wid = tid >> 6;
  const int wm = wid >> 1, wn = wid & 1;
  const int lr = lane & 15, lk = (lane >> 4) * 8;
  const int rbase = blockIdx.x * 64 + wm * 32 + lr;

  f32x4 acc[2][4];
  #pragma unroll
  for(int m = 0; m < 2; m++)
    #pragma unroll
    for(int n = 0; n < 4; n++) acc[m][n] = (f32x4){0.f, 0.f, 0.f, 0.f};

  for(int ks = 0; ks < 8; ks++){
    const __bf16* src = (ks < 4) ? Sa : Sx;
    const int kb = (ks & 3) * 32 + lk;
    bf16x8 a[2], b[4];
    #pragma unroll
    for(int m = 0; m < 2; m++){
      int r = rbase + m * 16; if(r > N_NODES - 1) r = N_NODES - 1;
      a[m] = *(const bf16x8*)(src + (size_t)r * 128 + kb);
    }
    #pragma unroll
    for(int n = 0; n < 4; n++)
      b[n] = *(const bf16x8*)(W1f + (((ks * 8 + wn * 4 + n) * 64 + lane) << 3));
    #pragma unroll
    for(int m = 0; m < 2; m++)
      #pragma unroll
      for(int n = 0; n < 4; n++)
        acc[m][n] = __builtin_amdgcn_mfma_f32_16x16x32_bf16(a[m], b[n], acc[m][n], 0, 0, 0);
  }

  #pragma unroll
  for(int n = 0; n < 4; n++){
    int gc = wn * 64 + n * 16 + lr;
    float bias = b1[gc];
    float ps = 0.f, pq = 0.f;
    #pragma unroll
    for(int m = 0; m < 2; m++){
      int gr0 = blockIdx.x * 64 + wm * 32 + m * 16 + (lane >> 4) * 4;
      #pragma unroll
      for(int i = 0; i < 4; i++){
        int r = gr0 + i;
        if(r < N_NODES){
          float h = acc[m][n][i] + bias;
          hpre[(size_t)r * HID + gc] = (__bf16)h;
          ps += h; pq += h * h;
        }
      }
    }
    ps += __shfl_xor(ps, 16); ps += __shfl_xor(ps, 32);
    pq += __shfl_xor(pq, 16); pq += __shfl_xor(pq, 32);
    if(lane < 16){
      bnred[wm][gc] = ps;
      bnred[wm][128 + gc] = pq;
    }
  }
  __syncthreads();
  atomicAdd(&bn_acc[tid], bnred[0][tid] + bnred[1][tid]);
}

// ---------------- GEMM 2 (MFMA): BN stats inline; BN+ReLU fused into A-frags ----------------

__global__ __launch_bounds__(256) void k_gemm2(
    const __bf16* __restrict__ hpre, const __bf16* __restrict__ W2f,
    const float* __restrict__ b2, const float* __restrict__ bn_acc,
    const float* __restrict__ gamma, const float* __restrict__ beta,
    __bf16* __restrict__ y2b, float* __restrict__ out){
  __shared__ float s_scale[HID], s_shift[HID];
  const int tid = threadIdx.x;
  if(tid < HID){
    float mean = bn_acc[tid] / (float)N_NODES;
    float var  = bn_acc[HID + tid] / (float)N_NODES - mean * mean;
    float rs   = rsqrtf(var + BN_EPS);
    float sc   = gamma[tid] * rs;
    s_scale[tid] = sc;
    s_shift[tid] = beta[tid] - mean * sc;
  }
  const int lane = tid & 63, wid = tid >> 6;
  const int wm = wid >> 1, wn = wid & 1;
  const int lr = lane & 15, lk = (lane >> 4) * 8;
  const int rbase = blockIdx.x * 64 + wm * 32 + lr;

  f32x4 acc[2][4];
  #pragma unroll
  for(int m = 0; m < 2; m++)
    #pragma unroll
    for(int n = 0; n < 4; n++) acc[m][n] = (f32x4){0.f, 0.f, 0.f, 0.f};
  __syncthreads();

  for(int ks = 0; ks < 4; ks++){
    int k0 = ks * 32 + lk;
    f32x4 sc0 = *(const f32x4*)(s_scale + k0);
    f32x4 sc1 = *(const f32x4*)(s_scale + k0 + 4);
    f32x4 sh0 = *(const f32x4*)(s_shift + k0);
    f32x4 sh1 = *(const f32x4*)(s_shift + k0 + 4);
    bf16x8 a[2], b[4];
    #pragma unroll
    for(int m = 0; m < 2; m++){
      int r = rbase + m * 16; if(r > N_NODES - 1) r = N_NODES - 1;
      bf16x8 hv = *(const bf16x8*)(hpre + (size_t)r * HID + k0);
      bf16x8 af;
      #pragma unroll
      for(int i = 0; i < 4; i++){
        af[i]     = (__bf16)fmaxf(0.f, fmaf((float)hv[i],     sc0[i], sh0[i]));
        af[4 + i] = (__bf16)fmaxf(0.f, fmaf((float)hv[4 + i], sc1[i], sh1[i]));
      }
      a[m] = af;
    }
    #pragma unroll
    for(int n = 0; n < 4; n++)
      b[n] = *(const bf16x8*)(W2f + (((ks * 8 + wn * 4 + n) * 64 + lane) << 3));
    #pragma unroll
    for(int m = 0; m < 2; m++)
      #pragma unroll
      for(int n = 0; n < 4; n++)
        acc[m][n] = __builtin_amdgcn_mfma_f32_16x16x32_bf16(a[m], b[n], acc[m][n], 0, 0, 0);
  }

  #pragma unroll
  for(int n = 0; n < 4; n++){
    int c = n * 16 + lr;
    float bias = (wn == 1) ? b2[c] : 0.f;
    #pragma unroll
    for(int m = 0; m < 2; m++){
      int gr0 = blockIdx.x * 64 + wm * 32 + m * 16 + (lane >> 4) * 4;
      #pragma unroll
      for(int i = 0; i < 4; i++){
        int r = gr0 + i;
        if(r < N_NODES){
          if(wn == 0) y2b[(size_t)r * F_OUT + c] = (__bf16)acc[m][n][i];
          else        out[(size_t)r * F_OUT + c] = acc[m][n][i] + bias;
        }
      }
    }
  }
}

// ---------------- SpMM 2: out += A @ y2 (bf16 gather, 4 edges per half-wave iter) ----------------

__global__ __launch_bounds__(256) void k_spmm2(const __bf16* __restrict__ y2b,
    const int2* __restrict__ epack, const int* __restrict__ rp, float* __restrict__ out){
  int w    = (int)((blockIdx.x * blockDim.x + threadIdx.x) >> 6);
  int lane = threadIdx.x & 63;
  if(w >= N_NODES) return;
  int beg = rp[w], end = rp[w + 1];
  int half = lane >> 5, li = lane & 31;
  float a0 = 0.f, a1 = 0.f;
  int e = beg + half;
  for(; e + 6 < end; e += 8){
    int2 p0 = epack[e],     p1 = epack[e + 2];
    int2 p2 = epack[e + 4], p3 = epack[e + 6];
    unsigned u0 = *(const unsigned*)(y2b + (size_t)p0.y * F_OUT + li * 2);
    unsigned u1 = *(const unsigned*)(y2b + (size_t)p1.y * F_OUT + li * 2);
    unsigned u2 = *(const unsigned*)(y2b + (size_t)p2.y * F_OUT + li * 2);
    unsigned u3 = *(const unsigned*)(y2b + (size_t)p3.y * F_OUT + li * 2);
    float w0 = __int_as_float(p0.x), w1 = __int_as_float(p1.x);
    float w2 = __int_as_float(p2.x), w3 = __int_as_float(p3.x);
    a0 = fmaf(w0, bflo(u0), a0); a1 = fmaf(w0, bfhi(u0), a1);
    a0 = fmaf(w1, bflo(u1), a0); a1 = fmaf(w1, bfhi(u1), a1);
    a0 = fmaf(w2, bflo(u2), a0); a1 = fmaf(w2, bfhi(u2), a1);
    a0 = fmaf(w3, bflo(u3), a0); a1 = fmaf(w3, bfhi(u3), a1);
  }
  for(; e < end; e += 2){
    int2 p = epack[e];
    float wt = __int_as_float(p.x);
    unsigned u = *(const unsigned*)(y2b + (size_t)p.y * F_OUT + li * 2);
    a0 = fmaf(wt, bflo(u), a0); a1 = fmaf(wt, bfhi(u), a1);
  }
  a0 += __shfl_xor(a0, 32);
  a1 += __shfl_xor(a1, 32);
  if(lane < 32){
    float2 o = *(float2*)(out + (size_t)w * F_OUT + li * 2);
    o.x += a0; o.y += a1;
    *(float2*)(out + (size_t)w * F_OUT + li * 2) = o;
  }
}

// ---------------- launch ----------------

extern "C" void kernel_launch(void* const* d_in, const int* in_sizes, int n_in,
                              void* d_out, int out_size, void* d_ws, size_t ws_size,
                              hipStream_t stream){
  const float* X     = (const float*)d_in[0];
  const float* W1    = (const float*)d_in[1];
  const float* b1    = (const float*)d_in[2];
  const float* gamma = (const float*)d_in[3];
  const float* beta  = (const float*)d_in[4];
  const float* W2    = (const float*)d_in[5];
  const float* b2    = (const float*)d_in[6];
  const float* evals = (const float*)d_in[7];
  const int*   esrc  = (const int*)d_in[8];
  const int*   edst  = (const int*)d_in[9];
  float* out = (float*)d_out;

  char* ws = (char*)d_ws;
  size_t off = 0;
  auto carve = [&](size_t bytes) -> char* {
    off = align_up(off, 256);
    char* p = ws + off;
    off += bytes;
    return p;
  };
  int*     Hcr    = (int*)    carve((size_t)NCHUNKS * NRANGES * 4);
  int*     rtot   = (int*)    carve((size_t)NRANGES * 4);
  int*     rp     = (int*)    carve(((size_t)N_NODES + 1) * 4);
  float*   bn_acc = (float*)  carve(256 * 4);
  int2*    staged = (int2*)   carve((size_t)N_EDGES * 8);
  int2*    epack  = (int2*)   carve((size_t)N_EDGES * 8);
  __bf16*  W1f    = (__bf16*) carve((size_t)4096 * 8 * 2);
  __bf16*  W2f    = (__bf16*) carve((size_t)2048 * 8 * 2);
  __bf16*  Sa     = (__bf16*) carve((size_t)N_NODES * 128 * 2);
  __bf16*  Sx     = (__bf16*) carve((size_t)N_NODES * 128 * 2);
  __bf16*  hpre   = (__bf16*) carve((size_t)N_NODES * HID * 2);
  __bf16*  y2b    = (__bf16*) carve((size_t)N_NODES * F_OUT * 2);

  k_setup<<<NCHUNKS + CVT_BLOCKS + PREPW_BLOCKS, 256, 0, stream>>>(
      edst, X, W1, W2, Hcr, Sx, W1f, W2f, bn_acc);
  k_scanR<<<NRANGES, 256, 0, stream>>>(Hcr, rtot);
  k_pass2<<<NCHUNKS, 256, 0, stream>>>(edst, esrc, evals, Hcr, rtot, staged);
  k_pass3<<<NRANGES, 256, 0, stream>>>(staged, rtot, epack, rp);

  k_spmm1<<<N_NODES / 4, 256, 0, stream>>>(Sx, Sa, epack, rp);
  k_gemm1<<<(N_NODES + 63) / 64, 256, 0, stream>>>(Sa, Sx, W1f, b1, hpre, bn_acc);
  k_gemm2<<<(N_NODES + 63) / 64, 256, 0, stream>>>(hpre, W2f, b2, bn_acc, gamma, beta, y2b, out);
  k_spmm2<<<N_NODES / 4, 256, 0, stream>>>(y2b, epack, rp, out);
}